// Round 4
// baseline (577.273 us; speedup 1.0000x reference)
//
#include <hip/hip_runtime.h>

// ---------------------------------------------------------------------------
// Earth padding of 5 strips (B=1, C=256) + edge-row cross-strip convs.
// Outputs (concatenated): (256,34,364)(256,64,724)(256,184,1444)(256,64,724)(256,34,364)
//
// Round-4: ONE kernel, 1024 persistent blocks (4/CU resident):
//   [0,540)     conv blocks: each runs one convT unit (u=bx) + one fwd unit (u=bx+540)
//   [540,840)   strip2 row-copies (300)
//   [840,912)   strip1 row-copies (72)
//   [912,984)   strip3 row-copies (72)
//   [984,1002)  strip0 row-copies (18)
//   [1002,1020) strip4 row-copies (18)
//   [1020,1024) zero rows of strip0/strip4
// Weights read directly from the input tensors (no transpose pass):
//   fwd:   wo[oc][ic][k] -> thread t streams contiguous float4s
//   convT: wi[ic][oc][k] -> thread t reads 5 contiguous floats per ic
// Both software-pipelined (next ic-chunk loads during current FMAs).
// ---------------------------------------------------------------------------

struct ConvJob {
  const float* x; const float* w; const float* bias; float* out;
  int Hin, Win, r0, Hout, Wcore, h0, blk_start;
};

struct MegaParams {
  ConvJob j[8];
  const float* in0; const float* in1; const float* in2; const float* in3; const float* in4;
  float* o0; float* o1; float* o2; float* o3; float* o4;
};

// --- row-based pad-copy: wave owns a row; circular width pad via lane-0 tail ---
template <int H, int W>
__device__ __forceinline__ void copy_strip_rows(const float* __restrict__ in,
                                                float* __restrict__ out,
                                                int lb, int nb, int t) {
  constexpr int WO4 = W / 4 + 1;            // (W+4)/4
  constexpr int NROWS = 256 * H;
  int wave = t >> 6, lane = t & 63;
  for (int row = lb * 4 + wave; row < NROWS; row += nb * 4) {
    int c = row / H;                        // constexpr division (magic mul)
    const float* src = in + (size_t)row * W;
    float* dst = out + (size_t)(row + c * 4 + 2) * (W + 4);
#pragma unroll 2
    for (int w4 = 1 + lane; w4 < WO4 - 1; w4 += 64) {
      const float* p = src + w4 * 4;
      float2 a = *(const float2*)(p - 2);
      float2 b = *(const float2*)(p);
      *(float4*)(dst + w4 * 4) = make_float4(a.x, a.y, b.x, b.y);
    }
    if (lane == 0) {
      // dst[0..3] == dst[W..W+3] == {x[W-2], x[W-1], x[0], x[1]}
      float2 E = *(const float2*)(src + W - 2);
      float2 F = *(const float2*)(src);
      float4 v = make_float4(E.x, E.y, F.x, F.y);
      *(float4*)(dst) = v;
      *(float4*)(dst + W) = v;
    }
  }
}

// --- fwd conv unit: out[u] = b + sum_ic sum_k w[k]*x[(2u+k-2) mod Win], 8 u ---
__device__ __forceinline__ void conv_fwd(const ConvJob jb, int local, int t, float* xs) {
  int tile = local >> 1;
  int r = local & 1;
  const int Win = jb.Win;
  const float* xrow = jb.x + ((size_t)(t * jb.Hin + jb.r0 + r)) * Win;
  const float* wbase = jb.w + (size_t)t * 1280;     // wo[oc=t][ic][k], contiguous
  const int Wop = jb.Wcore + 4;
  float* orow = jb.out + ((size_t)(t * jb.Hout + jb.h0 + r)) * Wop;

  int u0 = tile * 8;
  int cb = 2 * u0 - 2;
#pragma unroll
  for (int cc = 0; cc < 19; ++cc) {
    int col = cb + cc;
    col += (col < 0) ? Win : 0;
    col -= (col >= Win) ? Win : 0;
    xs[cc * 256 + t] = xrow[col];
  }
  __syncthreads();
  float bv = jb.bias[t];
  float acc[8];
#pragma unroll
  for (int i = 0; i < 8; ++i) acc[i] = bv;
  float4 wv[5];
#pragma unroll
  for (int q = 0; q < 5; ++q) wv[q] = *(const float4*)(wbase + 4 * q);
  for (int ic0 = 0; ic0 < 256; ic0 += 4) {
    float4 wn[5];
    if (ic0 + 4 < 256) {
      const float* wp = wbase + (ic0 + 4) * 5;
#pragma unroll
      for (int q = 0; q < 5; ++q) wn[q] = *(const float4*)(wp + 4 * q);
    }
    const float* wf = (const float*)wv;               // static indexing only
#pragma unroll
    for (int cc = 0; cc < 19; ++cc) {
      float4 xq = *(const float4*)&xs[cc * 256 + ic0];
#pragma unroll
      for (int i = 0; i < 8; ++i) {
        int k = cc - 2 * i;                           // column cc serves out i, tap k
        if (k >= 0 && k < 5)
          acc[i] += wf[k] * xq.x + wf[5 + k] * xq.y + wf[10 + k] * xq.z + wf[15 + k] * xq.w;
      }
    }
#pragma unroll
    for (int q = 0; q < 5; ++q) wv[q] = wn[q];
  }
#pragma unroll
  for (int i = 0; i < 8; ++i) {
    int g = u0 + i;
    float vv = acc[i];
    orow[2 + g] = vv;
    if (g < 2) orow[jb.Wcore + 2 + g] = vv;
    if (g >= jb.Wcore - 2) orow[g - (jb.Wcore - 2)] = vv;
  }
}

// --- convT unit: out[m] = sum_ic sum_{k==m mod 2} w[k]*x[((m+2-k)/2) mod Win], 16 m ---
__device__ __forceinline__ void conv_tr(const ConvJob jb, int local, int t, float* xs) {
  int tile = local >> 1;
  int r = local & 1;
  const int Win = jb.Win;
  const float* xrow = jb.x + ((size_t)(t * jb.Hin + jb.r0 + r)) * Win;
  const float* wbase = jb.w + (size_t)t * 5;        // wi[ic][oc=t][k]: elem ic*1280 + k
  const int Wop = jb.Wcore + 4;
  float* orow = jb.out + ((size_t)(t * jb.Hout + jb.h0 + r)) * Wop;

  int m0 = tile * 16;
  int j0 = (m0 >> 1) - 1;
#pragma unroll
  for (int cc = 0; cc < 10; ++cc) {
    int col = j0 + cc;
    col += (col < 0) ? Win : 0;
    col -= (col >= Win) ? Win : 0;
    xs[cc * 256 + t] = xrow[col];
  }
  __syncthreads();
  float acc[16];
#pragma unroll
  for (int i = 0; i < 16; ++i) acc[i] = 0.f;
  float w[20];
#pragma unroll
  for (int i = 0; i < 4; ++i)
#pragma unroll
    for (int k = 0; k < 5; ++k) w[i * 5 + k] = wbase[(size_t)i * 1280 + k];
  for (int ic0 = 0; ic0 < 256; ic0 += 4) {
    float wn[20];
    if (ic0 + 4 < 256) {
#pragma unroll
      for (int i = 0; i < 4; ++i)
#pragma unroll
        for (int k = 0; k < 5; ++k) wn[i * 5 + k] = wbase[(size_t)(ic0 + 4 + i) * 1280 + k];
    }
#pragma unroll
    for (int cc = 0; cc < 10; ++cc) {
      float4 xq = *(const float4*)&xs[cc * 256 + ic0];
#pragma unroll
      for (int ml = 0; ml < 16; ++ml) {
        int k = ml + 4 - 2 * cc;                      // column cc serves out ml, tap k
        if (k >= 0 && k < 5)
          acc[ml] += w[k] * xq.x + w[5 + k] * xq.y + w[10 + k] * xq.z + w[15 + k] * xq.w;
      }
    }
#pragma unroll
    for (int e = 0; e < 20; ++e) w[e] = wn[e];
  }
#pragma unroll
  for (int i = 0; i < 16; ++i) {
    int g = m0 + i;
    float vv = acc[i];
    orow[2 + g] = vv;
    if (g < 2) orow[jb.Wcore + 2 + g] = vv;
    if (g >= jb.Wcore - 2) orow[g - (jb.Wcore - 2)] = vv;
  }
}

// --- the persistent mega kernel ---
__global__ __launch_bounds__(256, 4) void mega_kernel(MegaParams p) {
  __shared__ float xs[19 * 256];            // 19.5 KB -> 4 blocks/CU uses 78 KB
  int bx = blockIdx.x;
  int t = threadIdx.x;
  if (bx < 540) {
    // convT unit u = bx (jobs 0..3)
    int u = bx;
    int ji = (u >= 450) ? 3 : (u >= 360) ? 2 : (u >= 180) ? 1 : 0;
    conv_tr(p.j[ji], u - p.j[ji].blk_start, t, xs);
    __syncthreads();                        // xs reuse barrier
    // fwd unit u2 = bx + 540 (jobs 4..7)
    int u2 = bx + 540;
    int j2 = (u2 >= 990) ? 7 : (u2 >= 900) ? 6 : (u2 >= 720) ? 5 : 4;
    conv_fwd(p.j[j2], u2 - p.j[j2].blk_start, t, xs);
  } else if (bx < 840) {
    copy_strip_rows<180, 1440>(p.in2, p.o2, bx - 540, 300, t);
  } else if (bx < 912) {
    copy_strip_rows<60, 720>(p.in1, p.o1, bx - 840, 72, t);
  } else if (bx < 984) {
    copy_strip_rows<60, 720>(p.in3, p.o3, bx - 912, 72, t);
  } else if (bx < 1002) {
    copy_strip_rows<30, 360>(p.in0, p.o0, bx - 984, 18, t);
  } else if (bx < 1020) {
    copy_strip_rows<30, 360>(p.in4, p.o4, bx - 1002, 18, t);
  } else {
    // zero rows: strip0 rows 0,1 ; strip4 rows 32,33  (1024 rows of 91 float4)
    int lb = bx - 1020;                     // 0..3
    int wave = t >> 6, lane = t & 63;
    for (int row = lb * 4 + wave; row < 1024; row += 16) {
      int strip = row >> 9;
      int cr = row & 511;
      int c = cr >> 1, r = cr & 1;
      float* dst = strip ? p.o4 + (size_t)(c * 34 + 32 + r) * 364
                         : p.o0 + (size_t)(c * 34 + r) * 364;
      for (int w4 = lane; w4 < 91; w4 += 64)
        *(float4*)(dst + w4 * 4) = make_float4(0.f, 0.f, 0.f, 0.f);
    }
  }
}

extern "C" void kernel_launch(void* const* d_in, const int* in_sizes, int n_in,
                              void* d_out, int out_size, void* d_ws, size_t ws_size,
                              hipStream_t stream) {
  const float* s0 = (const float*)d_in[0];   // (256,30,360)
  const float* s1 = (const float*)d_in[1];   // (256,60,720)
  const float* s2 = (const float*)d_in[2];   // (256,180,1440)
  const float* s3 = (const float*)d_in[3];   // (256,60,720)
  const float* s4 = (const float*)d_in[4];   // (256,30,360)
  const float* wi0 = (const float*)d_in[5];  // (256,256,1,5) [ic][oc][k]
  const float* wi1 = (const float*)d_in[6];
  const float* wo0 = (const float*)d_in[7];  // (256,256,1,5) [oc][ic][k]
  const float* bo0 = (const float*)d_in[8];
  const float* wo1 = (const float*)d_in[9];
  const float* bo1 = (const float*)d_in[10];

  float* out = (float*)d_out;
  float* out0 = out;                 // (256,34,364)
  float* out1 = out + 3168256;       // (256,64,724)
  float* out2 = out + 15030272;      // (256,184,1444)
  float* out3 = out + 83048448;      // (256,64,724)
  float* out4 = out + 94910464;      // (256,34,364)

  MegaParams mp;
  //           x    w    bias    out   Hin  Win   r0  Hout Wcore h0  blk_start
  mp.j[0] = {s1, wi0, nullptr, out2,  60,  720,  58, 184, 1440,   0,   0}; // convT -> out2 top    (180 units)
  mp.j[1] = {s3, wi0, nullptr, out2,  60,  720,   0, 184, 1440, 182, 180}; // convT -> out2 bottom (180)
  mp.j[2] = {s0, wi1, nullptr, out1,  30,  360,  28,  64,  720,   0, 360}; // convT -> out1 top    ( 90)
  mp.j[3] = {s4, wi1, nullptr, out3,  30,  360,   0,  64,  720,  62, 450}; // convT -> out3 bottom ( 90)
  mp.j[4] = {s2, wo0, bo0,     out1, 180, 1440,   0,  64,  720,  62, 540}; // fwd   -> out1 bottom (180)
  mp.j[5] = {s2, wo0, bo0,     out3, 180, 1440, 178,  64,  720,   0, 720}; // fwd   -> out3 top    (180)
  mp.j[6] = {s1, wo1, bo1,     out0,  60,  720,   0,  34,  360,  32, 900}; // fwd   -> out0 bottom ( 90)
  mp.j[7] = {s3, wo1, bo1,     out4,  60,  720,  58,  34,  360,   0, 990}; // fwd   -> out4 top    ( 90)
  mp.in0 = s0; mp.in1 = s1; mp.in2 = s2; mp.in3 = s3; mp.in4 = s4;
  mp.o0 = out0; mp.o1 = out1; mp.o2 = out2; mp.o3 = out3; mp.o4 = out4;

  mega_kernel<<<1024, 256, 0, stream>>>(mp);
}

// Round 5
// 361.753 us; speedup vs baseline: 1.5958x; 1.5958x over previous
//
#include <hip/hip_runtime.h>

// ---------------------------------------------------------------------------
// Earth padding of 5 strips (B=1, C=256) + edge-row cross-strip convs.
// Outputs (concatenated): (256,34,364)(256,64,724)(256,184,1444)(256,64,724)(256,34,364)
//
// Round-5:
//   kernel 1: weight transpose -> wt[ic][k][oc] (lane-coalesced) + zero job ctr
//   kernel 2: mega, 1024 persistent blocks, __launch_bounds__(256,4):
//     blocks [0,540): conv units (convT u=bx, then fwd u=bx+540), scalar
//                     double-buffered weights (NO vector-pointer punning!)
//     then ALL blocks enter a work-stealing loop over 93184 row-jobs
//     (5 strip pad-copies + 1024 zero-rows), 8 rows per atomic grab.
// Disjoint write sets -> no ordering needed.
// ---------------------------------------------------------------------------

struct ConvJob {
  const float* x; const float* wt; const float* bias; float* out;
  int Hin, Win, r0, Hout, Wcore, h0, blk_start;
};

struct MegaParams {
  ConvJob j[8];
  const float* in0; const float* in1; const float* in2; const float* in3; const float* in4;
  float* o0; float* o1; float* o2; float* o3; float* o4;
  unsigned* ctr;
};

struct WTParams { const float* src[4]; float* dst[4]; unsigned* ctr; };

// --- fused weight transpose: dst[(ic*5+k)*256 + oc]; also zeroes the job ctr ---
// which 0,1: src is wi [ic][oc][1][k] ; which 2,3: src is wo [oc][ic][1][k]
__global__ __launch_bounds__(256) void transpose_all_kernel(WTParams p) {
  if (blockIdx.x == 0 && threadIdx.x == 0) *p.ctr = 0u;
  int b = blockIdx.x;                       // 5120 blocks = 4 * 1280
  int which = b / 1280;
  int idx = (b - which * 1280) * 256 + threadIdx.x;
  int oc = idx & 255;
  int q = idx >> 8;
  int k = q % 5;
  int ic = q / 5;
  const float* s = p.src[which];
  float v = (which < 2) ? s[(ic * 256 + oc) * 5 + k] : s[(oc * 256 + ic) * 5 + k];
  p.dst[which][idx] = v;
}

// --- one padded row copy: wave owns the row; circular width pad via lane-0 tail ---
template <int H, int W>
__device__ __forceinline__ void copy_row(const float* __restrict__ in,
                                         float* __restrict__ out, int rl, int lane) {
  int c = rl / H;                           // constexpr division (magic mul)
  const float* src = in + (size_t)rl * W;
  float* dst = out + (size_t)(rl + c * 4 + 2) * (W + 4);
  for (int w4 = 1 + lane; w4 < W / 4; w4 += 64) {
    const float* q = src + w4 * 4;
    float2 a = *(const float2*)(q - 2);
    float2 b = *(const float2*)(q);
    *(float4*)(dst + w4 * 4) = make_float4(a.x, a.y, b.x, b.y);
  }
  if (lane == 0) {
    // dst[0..3] == dst[W..W+3] == {x[W-2], x[W-1], x[0], x[1]}
    float2 E = *(const float2*)(src + W - 2);
    float2 F = *(const float2*)(src);
    float4 v = make_float4(E.x, E.y, F.x, F.y);
    *(float4*)(dst) = v;
    *(float4*)(dst + W) = v;
  }
}

__device__ __forceinline__ void zero_row(const MegaParams& p, int z, int lane) {
  int strip = z >> 9, cr = z & 511, c = cr >> 1, r = cr & 1;
  float* dst = strip ? p.o4 + (size_t)(c * 34 + 32 + r) * 364
                     : p.o0 + (size_t)(c * 34 + r) * 364;
  for (int w4 = lane; w4 < 91; w4 += 64)
    *(float4*)(dst + w4 * 4) = make_float4(0.f, 0.f, 0.f, 0.f);
}

// row-job space: [0,46080) s2 | [,61440) s1 | [,76800) s3 | [,84480) s0
//                | [,92160) s4 | [,93184) zero rows
__device__ __forceinline__ void do_row(const MegaParams& p, int gid, int lane) {
  if (gid < 46080)      copy_row<180, 1440>(p.in2, p.o2, gid, lane);
  else if (gid < 61440) copy_row<60, 720>(p.in1, p.o1, gid - 46080, lane);
  else if (gid < 76800) copy_row<60, 720>(p.in3, p.o3, gid - 61440, lane);
  else if (gid < 84480) copy_row<30, 360>(p.in0, p.o0, gid - 76800, lane);
  else if (gid < 92160) copy_row<30, 360>(p.in4, p.o4, gid - 84480, lane);
  else                  zero_row(p, gid - 92160, lane);
}

// --- convT unit: out[m] = sum_ic sum_{k==m mod 2} w[k]*x[((m+2-k)/2) mod Win], 16 m ---
__device__ __forceinline__ void conv_tr(const ConvJob jb, int local, int t, float* xs) {
  int tile = local >> 1;
  int r = local & 1;
  const int Win = jb.Win;
  const float* xrow = jb.x + ((size_t)(t * jb.Hin + jb.r0 + r)) * Win;
  const float* wt = jb.wt + t;              // wt[(ic*5+k)*256 + t], lane-coalesced
  const int Wop = jb.Wcore + 4;
  float* orow = jb.out + ((size_t)(t * jb.Hout + jb.h0 + r)) * Wop;

  int m0 = tile * 16;
  int j0 = (m0 >> 1) - 1;
#pragma unroll
  for (int cc = 0; cc < 10; ++cc) {
    int col = j0 + cc;
    col += (col < 0) ? Win : 0;
    col -= (col >= Win) ? Win : 0;
    xs[cc * 256 + t] = xrow[col];
  }
  __syncthreads();
  float acc[16];
#pragma unroll
  for (int i = 0; i < 16; ++i) acc[i] = 0.f;
  float w[20], wn[20];
#pragma unroll
  for (int e = 0; e < 20; ++e) w[e] = wt[e * 256];           // ic 0..3
  for (int ic0 = 0; ic0 < 256; ic0 += 4) {
    if (ic0 + 4 < 256) {
#pragma unroll
      for (int e = 0; e < 20; ++e) wn[e] = wt[(size_t)((ic0 + 4) * 5 + e) * 256];
    }
#pragma unroll
    for (int cc = 0; cc < 10; ++cc) {
      float4 xq = *(const float4*)&xs[cc * 256 + ic0];
#pragma unroll
      for (int ml = 0; ml < 16; ++ml) {
        int k = ml + 4 - 2 * cc;            // column cc serves out ml with tap k
        if (k >= 0 && k < 5)
          acc[ml] += w[k] * xq.x + w[5 + k] * xq.y + w[10 + k] * xq.z + w[15 + k] * xq.w;
      }
    }
#pragma unroll
    for (int e = 0; e < 20; ++e) w[e] = wn[e];
  }
#pragma unroll
  for (int i = 0; i < 16; ++i) {
    int g = m0 + i;
    float vv = acc[i];
    orow[2 + g] = vv;
    if (g < 2) orow[jb.Wcore + 2 + g] = vv;
    if (g >= jb.Wcore - 2) orow[g - (jb.Wcore - 2)] = vv;
  }
}

// --- fwd conv unit: out[u] = b + sum_ic sum_k w[k]*x[(2u+k-2) mod Win], 8 u ---
__device__ __forceinline__ void conv_fwd(const ConvJob jb, int local, int t, float* xs) {
  int tile = local >> 1;
  int r = local & 1;
  const int Win = jb.Win;
  const float* xrow = jb.x + ((size_t)(t * jb.Hin + jb.r0 + r)) * Win;
  const float* wt = jb.wt + t;              // wt[(ic*5+k)*256 + t], lane-coalesced
  const int Wop = jb.Wcore + 4;
  float* orow = jb.out + ((size_t)(t * jb.Hout + jb.h0 + r)) * Wop;

  int u0 = tile * 8;
  int cb = 2 * u0 - 2;
#pragma unroll
  for (int cc = 0; cc < 19; ++cc) {
    int col = cb + cc;
    col += (col < 0) ? Win : 0;
    col -= (col >= Win) ? Win : 0;
    xs[cc * 256 + t] = xrow[col];
  }
  __syncthreads();
  float bv = jb.bias[t];
  float acc[8];
#pragma unroll
  for (int i = 0; i < 8; ++i) acc[i] = bv;
  float w[20], wn[20];
#pragma unroll
  for (int e = 0; e < 20; ++e) w[e] = wt[e * 256];           // ic 0..3
  for (int ic0 = 0; ic0 < 256; ic0 += 4) {
    if (ic0 + 4 < 256) {
#pragma unroll
      for (int e = 0; e < 20; ++e) wn[e] = wt[(size_t)((ic0 + 4) * 5 + e) * 256];
    }
#pragma unroll
    for (int cc = 0; cc < 19; ++cc) {
      float4 xq = *(const float4*)&xs[cc * 256 + ic0];
#pragma unroll
      for (int i = 0; i < 8; ++i) {
        int k = cc - 2 * i;                 // column cc serves out i with tap k
        if (k >= 0 && k < 5)
          acc[i] += w[k] * xq.x + w[5 + k] * xq.y + w[10 + k] * xq.z + w[15 + k] * xq.w;
      }
    }
#pragma unroll
    for (int e = 0; e < 20; ++e) w[e] = wn[e];
  }
#pragma unroll
  for (int i = 0; i < 8; ++i) {
    int g = u0 + i;
    float vv = acc[i];
    orow[2 + g] = vv;
    if (g < 2) orow[jb.Wcore + 2 + g] = vv;
    if (g >= jb.Wcore - 2) orow[g - (jb.Wcore - 2)] = vv;
  }
}

// --- the persistent mega kernel: conv first, then work-stealing copies ---
__global__ __launch_bounds__(256, 4) void mega_kernel(MegaParams p) {
  __shared__ float xs[19 * 256];            // 19.5 KB -> 4 blocks/CU = 78 KB
  int bx = blockIdx.x;
  int t = threadIdx.x;
  if (bx < 540) {
    int ji = (bx >= 450) ? 3 : (bx >= 360) ? 2 : (bx >= 180) ? 1 : 0;
    conv_tr(p.j[ji], bx - p.j[ji].blk_start, t, xs);
    __syncthreads();                        // xs reuse barrier
    int u2 = bx + 540;
    int j2 = (u2 >= 990) ? 7 : (u2 >= 900) ? 6 : (u2 >= 720) ? 5 : 4;
    conv_fwd(p.j[j2], u2 - p.j[j2].blk_start, t, xs);
  }
  // work-stealing copy loop: 11648 groups x 8 rows = 93184 row-jobs
  int lane = t & 63;
  for (;;) {
    int g = 0;
    if (lane == 0) g = (int)atomicAdd(p.ctr, 1u);
    g = __shfl(g, 0, 64);
    if (g >= 11648) break;
    int base = g * 8;
    for (int r = 0; r < 8; ++r) do_row(p, base + r, lane);
  }
}

extern "C" void kernel_launch(void* const* d_in, const int* in_sizes, int n_in,
                              void* d_out, int out_size, void* d_ws, size_t ws_size,
                              hipStream_t stream) {
  const float* s0 = (const float*)d_in[0];   // (256,30,360)
  const float* s1 = (const float*)d_in[1];   // (256,60,720)
  const float* s2 = (const float*)d_in[2];   // (256,180,1440)
  const float* s3 = (const float*)d_in[3];   // (256,60,720)
  const float* s4 = (const float*)d_in[4];   // (256,30,360)
  const float* wi0 = (const float*)d_in[5];  // (256,256,1,5) [ic][oc][k]
  const float* wi1 = (const float*)d_in[6];
  const float* wo0 = (const float*)d_in[7];  // (256,256,1,5) [oc][ic][k]
  const float* bo0 = (const float*)d_in[8];
  const float* wo1 = (const float*)d_in[9];
  const float* bo1 = (const float*)d_in[10];

  float* out = (float*)d_out;
  float* out0 = out;                 // (256,34,364)
  float* out1 = out + 3168256;       // (256,64,724)
  float* out2 = out + 15030272;      // (256,184,1444)
  float* out3 = out + 83048448;      // (256,64,724)
  float* out4 = out + 94910464;      // (256,34,364)

  // workspace: [0] job counter, [16..] 4 transposed weight tables [ic][k][oc]
  unsigned* ctr = (unsigned*)d_ws;
  float* wt0 = (float*)d_ws + 16;
  float* wt1 = wt0 + 327680;
  float* wt2 = wt1 + 327680;
  float* wt3 = wt2 + 327680;

  WTParams wp;
  wp.src[0] = wi0; wp.src[1] = wi1; wp.src[2] = wo0; wp.src[3] = wo1;
  wp.dst[0] = wt0; wp.dst[1] = wt1; wp.dst[2] = wt2; wp.dst[3] = wt3;
  wp.ctr = ctr;
  transpose_all_kernel<<<5120, 256, 0, stream>>>(wp);

  MegaParams mp;
  //           x    wt   bias    out   Hin  Win   r0  Hout Wcore h0  blk_start
  mp.j[0] = {s1, wt0, nullptr, out2,  60,  720,  58, 184, 1440,   0,   0}; // convT -> out2 top    (180 units)
  mp.j[1] = {s3, wt0, nullptr, out2,  60,  720,   0, 184, 1440, 182, 180}; // convT -> out2 bottom (180)
  mp.j[2] = {s0, wt1, nullptr, out1,  30,  360,  28,  64,  720,   0, 360}; // convT -> out1 top    ( 90)
  mp.j[3] = {s4, wt1, nullptr, out3,  30,  360,   0,  64,  720,  62, 450}; // convT -> out3 bottom ( 90)
  mp.j[4] = {s2, wt2, bo0,     out1, 180, 1440,   0,  64,  720,  62, 540}; // fwd   -> out1 bottom (180)
  mp.j[5] = {s2, wt2, bo0,     out3, 180, 1440, 178,  64,  720,   0, 720}; // fwd   -> out3 top    (180)
  mp.j[6] = {s1, wt3, bo1,     out0,  60,  720,   0,  34,  360,  32, 900}; // fwd   -> out0 bottom ( 90)
  mp.j[7] = {s3, wt3, bo1,     out4,  60,  720,  58,  34,  360,   0, 990}; // fwd   -> out4 top    ( 90)
  mp.in0 = s0; mp.in1 = s1; mp.in2 = s2; mp.in3 = s3; mp.in4 = s4;
  mp.o0 = out0; mp.o1 = out1; mp.o2 = out2; mp.o3 = out3; mp.o4 = out4;
  mp.ctr = ctr;

  mega_kernel<<<1024, 256, 0, stream>>>(mp);
}